// Round 2
// baseline (1080.594 us; speedup 1.0000x reference)
//
#include <hip/hip_runtime.h>
#include <math.h>

#define BATCH 16
#define SEQLEN 4096
#define INPUT_DIM 57
#define D_MODEL 256
#define D_INNER 512
#define D_STATE 8
#define HEADDIM 16
#define NHEADS 32
#define CHUNK 8
#define NC (SEQLEN/CHUNK)          // 512
#define CONV_DIM 528               // D_INNER + 2*D_STATE
#define D_INPROJ 1072              // 2*D_INNER + 2*D_STATE + NHEADS
#define OUT_SIZE 6
#define NTOK (BATCH*SEQLEN)        // 65536

static __device__ const int tri_i_tab[36] = {0,1,1,2,2,2,3,3,3,3,4,4,4,4,4,5,5,5,5,5,5,6,6,6,6,6,6,6,7,7,7,7,7,7,7,7};
static __device__ const int tri_j_tab[36] = {0,0,1,0,1,2,0,1,2,3,0,1,2,3,4,0,1,2,3,4,5,0,1,2,3,4,5,6,0,1,2,3,4,5,6,7};

// ---------------------------------------------------------------------------
// P0: fold W_in into W_inproj (K=57 GEMM), fold W_out into W_cls (the big
// output GEMM is never needed: only mean_t(y) is). fp64 internally.
// ---------------------------------------------------------------------------
__global__ void precompute_kernel(const float* __restrict__ W_in,
                                  const float* __restrict__ b_in,
                                  const float* __restrict__ W_inproj,
                                  const float* __restrict__ W_out,
                                  const float* __restrict__ W_cls,
                                  float* __restrict__ WcT,    // [57][1072]
                                  float* __restrict__ b_comb, // [1072]
                                  float* __restrict__ W_oc)   // [6][512]
{
    int blk = blockIdx.x;
    int t = threadIdx.x;
    if (blk < D_INPROJ) {
        int n = blk;
        if (t < INPUT_DIM) {
            double acc = 0.0;
            for (int m = 0; m < D_MODEL; ++m)
                acc += (double)W_inproj[n*D_MODEL+m] * (double)W_in[m*INPUT_DIM+t];
            WcT[t*D_INPROJ + n] = (float)acc;
        } else if (t == INPUT_DIM) {
            double acc = 0.0;
            for (int m = 0; m < D_MODEL; ++m)
                acc += (double)W_inproj[n*D_MODEL+m] * (double)b_in[m];
            b_comb[n] = (float)acc;
        }
    } else {
        int d = blk - D_INPROJ;
        if (t < OUT_SIZE) {
            double acc = 0.0;
            for (int m = 0; m < D_MODEL; ++m)
                acc += (double)W_cls[t*D_MODEL+m] * (double)W_out[m*D_INNER+d];
            W_oc[t*D_INNER + d] = (float)acc;
        }
    }
}

// ---------------------------------------------------------------------------
// A1: per (batch, chunk) block. Fuses: in-projection micro-GEMM (11 halo+main
// tokens x 1072 cols x K=57), causal conv + silu, softplus(dt), cA cumsum,
// chunk-local attention (y_intra + D*x), silu(z) gating of the intra part +
// fp32 partial pooling, state contribution S, chunk_dec, C and exp(cA).
// ---------------------------------------------------------------------------
__global__ __launch_bounds__(256) void chunk_kernel(
    const float* __restrict__ x,       // [NTOK][57]
    const float* __restrict__ WcT,     // [57][1072]
    const float* __restrict__ bcomb,   // [1072]
    const float* __restrict__ conv_w,  // [528][4]
    const float* __restrict__ conv_b,  // [528]
    const float* __restrict__ dt_bias, // [32]
    const float* __restrict__ A_log,   // [32]
    const float* __restrict__ Dvec,    // [32]
    float* __restrict__ Sg,            // [B][NC][32][16][8]
    float* __restrict__ cdec,          // [B][NC][32]
    float* __restrict__ Ct,            // [NTOK][8]
    float* __restrict__ cAe_g,         // [NTOK][32]
    float* __restrict__ partial_intra) // [B*NC][512]
{
    __shared__ __attribute__((aligned(16))) float xsT[57][12];   // [k][slot]; slot r+1 holds row r (t0-3+r); slot0 dead
    __shared__ __attribute__((aligned(16))) float stage[11][560];// xBCdt cols (abs 512..1071), rows t0-3..t0+7
    __shared__ __attribute__((aligned(16))) float zsh[8][512];   // z for main tokens
    __shared__ __attribute__((aligned(16))) float xsilu[8][512];
    __shared__ float Bs[8][8], Cs[8][8];
    __shared__ float dts[8][32], cAl[8][32];
    __shared__ float CBl[8][8];
    __shared__ float scl[8][8][32];
    __shared__ float gco[8][32];

    const int bc  = blockIdx.x;            // b*NC + c
    const int b   = bc >> 9, c = bc & (NC-1);
    const int tid = threadIdx.x;
    const long t0 = (long)b*SEQLEN + (long)c*CHUNK;

    // ---- phase 1: stage x rows (t0-3 .. t0+7) transposed into LDS ----
    for (int idx = tid; idx < 11*INPUT_DIM; idx += 256) {
        int r = idx / INPUT_DIM, k = idx - r*INPUT_DIM;
        float v = (c == 0 && r < 3) ? 0.f : x[(t0 - 3 + r)*INPUT_DIM + k];
        xsT[k][r + 1] = v;
    }
    __syncthreads();

    // ---- phase 2: micro-GEMM.  z cols: tid, tid+256 (rows 3..10 only);
    //      xBCdt cols: tid, tid+256, (tid<48) tid+512 (all 11 rows) ----
    {
        const bool has2 = (tid < 48);
        const int  n2   = has2 ? tid + 512 : 512;   // stage col (abs col 1024+...)
        float accz0[8], accz1[8];
        float accx0[11], accx1[11], accx2[11];
        {
            const float bz0 = bcomb[tid], bz1 = bcomb[tid+256];
            const float bx0 = bcomb[512+tid], bx1 = bcomb[768+tid], bx2 = bcomb[512+n2];
            #pragma unroll
            for (int i = 0; i < 8; ++i) { accz0[i] = bz0; accz1[i] = bz1; }
            #pragma unroll
            for (int r = 0; r < 11; ++r) {
                float h0 = (c == 0 && r < 3) ? 0.f : 1.f;   // zero-pad halo rows of xBC for chunk 0
                accx0[r] = bx0*h0; accx1[r] = bx1*h0; accx2[r] = bx2*h0;
            }
        }
        for (int k = 0; k < INPUT_DIM; ++k) {
            const float4 va = *(const float4*)&xsT[k][0];
            const float4 vb = *(const float4*)&xsT[k][4];
            const float4 vc = *(const float4*)&xsT[k][8];
            const float* wrow = &WcT[(size_t)k*D_INPROJ];
            const float wz0 = wrow[tid], wz1 = wrow[tid+256];
            const float wx0 = wrow[512+tid], wx1 = wrow[768+tid], wx2 = wrow[512+n2];
            // main rows i=0..7 are slots 4..11 (vb, vc); halo rows 0..2 are slots 1..3 (va.y..va.w)
            const float xm0=vb.x, xm1=vb.y, xm2=vb.z, xm3=vb.w, xm4=vc.x, xm5=vc.y, xm6=vc.z, xm7=vc.w;
            accz0[0]+=wz0*xm0; accz0[1]+=wz0*xm1; accz0[2]+=wz0*xm2; accz0[3]+=wz0*xm3;
            accz0[4]+=wz0*xm4; accz0[5]+=wz0*xm5; accz0[6]+=wz0*xm6; accz0[7]+=wz0*xm7;
            accz1[0]+=wz1*xm0; accz1[1]+=wz1*xm1; accz1[2]+=wz1*xm2; accz1[3]+=wz1*xm3;
            accz1[4]+=wz1*xm4; accz1[5]+=wz1*xm5; accz1[6]+=wz1*xm6; accz1[7]+=wz1*xm7;
            accx0[0]+=wx0*va.y; accx0[1]+=wx0*va.z; accx0[2]+=wx0*va.w;
            accx1[0]+=wx1*va.y; accx1[1]+=wx1*va.z; accx1[2]+=wx1*va.w;
            accx2[0]+=wx2*va.y; accx2[1]+=wx2*va.z; accx2[2]+=wx2*va.w;
            accx0[3]+=wx0*xm0; accx0[4]+=wx0*xm1; accx0[5]+=wx0*xm2; accx0[6]+=wx0*xm3;
            accx0[7]+=wx0*xm4; accx0[8]+=wx0*xm5; accx0[9]+=wx0*xm6; accx0[10]+=wx0*xm7;
            accx1[3]+=wx1*xm0; accx1[4]+=wx1*xm1; accx1[5]+=wx1*xm2; accx1[6]+=wx1*xm3;
            accx1[7]+=wx1*xm4; accx1[8]+=wx1*xm5; accx1[9]+=wx1*xm6; accx1[10]+=wx1*xm7;
            accx2[3]+=wx2*xm0; accx2[4]+=wx2*xm1; accx2[5]+=wx2*xm2; accx2[6]+=wx2*xm3;
            accx2[7]+=wx2*xm4; accx2[8]+=wx2*xm5; accx2[9]+=wx2*xm6; accx2[10]+=wx2*xm7;
        }
        #pragma unroll
        for (int i = 0; i < 8; ++i) { zsh[i][tid] = accz0[i]; zsh[i][tid+256] = accz1[i]; }
        #pragma unroll
        for (int r = 0; r < 11; ++r) { stage[r][tid] = accx0[r]; stage[r][tid+256] = accx1[r]; }
        if (has2) {
            #pragma unroll
            for (int r = 0; r < 11; ++r) stage[r][tid+512] = accx2[r];
        }
    }
    __syncthreads();

    // ---- phase 3: causal conv(4) + silu over 528 channels, 8 tokens ----
    for (int ch = tid; ch < CONV_DIM; ch += 256) {
        const float w0 = conv_w[ch*4+0], w1 = conv_w[ch*4+1];
        const float w2 = conv_w[ch*4+2], w3 = conv_w[ch*4+3];
        const float cb = conv_b[ch];
        float s0 = stage[0][ch], s1 = stage[1][ch], s2 = stage[2][ch];
        #pragma unroll
        for (int i = 0; i < CHUNK; ++i) {
            float s3 = stage[3+i][ch];
            float v = cb + s0*w0 + s1*w1 + s2*w2 + s3*w3;
            v = v / (1.f + expf(-v));                 // silu
            if (ch < D_INNER)       xsilu[i][ch] = v;
            else if (ch < 520)      Bs[i][ch-512] = v;
            else { Cs[i][ch-520] = v; Ct[(t0+i)*8 + (ch-520)] = v; }
            s0 = s1; s1 = s2; s2 = s3;
        }
    }
    // ---- dt softplus (8 tokens x 32 heads) ----
    {
        int i = tid >> 5, h = tid & 31;
        float raw = stage[3+i][528+h] + dt_bias[h];
        dts[i][h] = (raw > 20.f) ? raw : log1pf(expf(raw));
    }
    __syncthreads();

    // ---- phase 4: cA cumsum + cdec + exp(cA); CB = C B^T ----
    if (tid < 32) {
        const int h = tid;
        const float Ah = -expf(A_log[h]);
        float ca = 0.f, e = 1.f;
        #pragma unroll
        for (int i = 0; i < CHUNK; ++i) {
            ca += dts[i][h] * Ah;
            cAl[i][h] = ca;
            e = expf(ca);
            cAe_g[(t0+i)*32 + h] = e;
        }
        cdec[bc*32 + h] = e;                          // exp(cA[7])
    } else if (tid < 96) {
        int ij = tid - 32, i = ij >> 3, j = ij & 7;
        float s = 0.f;
        #pragma unroll
        for (int n = 0; n < D_STATE; ++n) s += Cs[i][n]*Bs[j][n];
        CBl[i][j] = s;
    }
    __syncthreads();

    // ---- phase 4b: score coefficients (lower tri) + state-gather coeffs ----
    for (int idx = tid; idx < 36*32; idx += 256) {
        int pr = idx >> 5, h = idx & 31;
        int i = tri_i_tab[pr], j = tri_j_tab[pr];
        scl[i][j][h] = CBl[i][j] * expf(cAl[i][h] - cAl[j][h]) * dts[j][h];
    }
    {
        int j = tid >> 5, h = tid & 31;
        gco[j][h] = expf(cAl[7][h] - cAl[j][h]) * dts[j][h];
    }
    __syncthreads();

    // ---- phase 5: each thread owns head h, 2 consecutive p slots ----
    const int h  = tid >> 3;
    const int p0 = (tid & 7) * 2;
    const int d0 = tid * 2;                           // == h*16 + p0
    float2 xv[8];
    #pragma unroll
    for (int j = 0; j < CHUNK; ++j) xv[j] = *(const float2*)&xsilu[j][d0];
    const float Dv = Dvec[h];

    // intra: y_intra + D*x, then gate with silu(z) and pool over the 8 tokens
    float pa0 = 0.f, pa1 = 0.f;
    #pragma unroll
    for (int i = 0; i < CHUNK; ++i) {
        float a0 = Dv*xv[i].x, a1 = Dv*xv[i].y;
        #pragma unroll
        for (int j = 0; j < CHUNK; ++j) {
            if (j > i) break;
            float s = scl[i][j][h];
            a0 += s*xv[j].x; a1 += s*xv[j].y;
        }
        float2 zz = *(const float2*)&zsh[i][d0];
        float sz0 = zz.x / (1.f + expf(-zz.x));
        float sz1 = zz.y / (1.f + expf(-zz.y));
        pa0 += a0*sz0; pa1 += a1*sz1;
    }
    partial_intra[(size_t)bc*512 + d0]     = pa0;
    partial_intra[(size_t)bc*512 + d0 + 1] = pa1;

    // state contribution S[h][p][n]
    float tj0[8], tj1[8];
    #pragma unroll
    for (int j = 0; j < CHUNK; ++j) {
        float g = gco[j][h];
        tj0[j] = g*xv[j].x; tj1[j] = g*xv[j].y;
    }
    float sn0[8], sn1[8];
    #pragma unroll
    for (int n = 0; n < D_STATE; ++n) {
        float s = 0.f, t = 0.f;
        #pragma unroll
        for (int j = 0; j < CHUNK; ++j) { float bv = Bs[j][n]; s += tj0[j]*bv; t += tj1[j]*bv; }
        sn0[n] = s; sn1[n] = t;
    }
    size_t sb = ((size_t)bc*32 + h)*128 + (size_t)p0*8;
    *(float4*)&Sg[sb+0]  = make_float4(sn0[0],sn0[1],sn0[2],sn0[3]);
    *(float4*)&Sg[sb+4]  = make_float4(sn0[4],sn0[5],sn0[6],sn0[7]);
    *(float4*)&Sg[sb+8]  = make_float4(sn1[0],sn1[1],sn1[2],sn1[3]);
    *(float4*)&Sg[sb+12] = make_float4(sn1[4],sn1[5],sn1[6],sn1[7]);
}

// ---------------------------------------------------------------------------
// A2: fused inter-chunk state scan + y_inter pooling. 512 blocks = (b,h),
// 128 threads. Processes 8 chunks per barrier pair. z is recomputed from x
// (x is L3-resident) with per-thread weight registers.
// Roles: phase A thread=(p,n)=(tid>>3,tid&7); phase B thread=(i,p)=(tid>>4,tid&15).
// ---------------------------------------------------------------------------
__global__ __launch_bounds__(128) void scanpool_kernel(
    const float* __restrict__ x,       // [NTOK][57]
    const float* __restrict__ WcT,     // [57][1072]
    const float* __restrict__ bcomb,   // [1072]
    const float* __restrict__ Sg,      // [B][NC][32][128]
    const float* __restrict__ cdec,    // [B][NC][32]
    const float* __restrict__ Ct,      // [NTOK][8]
    const float* __restrict__ cAe,     // [NTOK][32]
    double* __restrict__ partial_inter)// [B][512]
{
    const int bh = blockIdx.x;
    const int b = bh >> 5, h = bh & 31;
    const int tid = threadIdx.x;
    const int pA = tid >> 3, nA = tid & 7;
    const int iB = tid >> 4, pB = tid & 15;

    __shared__ __attribute__((aligned(16))) float xls[8][8][60]; // [cc][token][k]
    __shared__ float hls[8][16][10];
    __shared__ float Cls[8][8][8];
    __shared__ float els[8][8];
    __shared__ double red[128];

    float w[57];
    #pragma unroll
    for (int k = 0; k < INPUT_DIM; ++k) w[k] = WcT[(size_t)k*D_INPROJ + h*HEADDIM + pB];
    const float zb = bcomb[h*HEADDIM + pB];

    float s = 0.f;
    double acc = 0.0;
    const size_t sgbase = ((size_t)(b*NC)*32 + h)*128 + tid;

    for (int cb = 0; cb < NC/8; ++cb) {
        const int c0 = cb*8;
        __syncthreads();
        // cooperative global -> LDS for 8 chunks
        for (int q = tid; q < 8*8*INPUT_DIM; q += 128) {
            int cc = q / (8*INPUT_DIM), j = q - cc*(8*INPUT_DIM);
            int r = j / INPUT_DIM, k = j - r*INPUT_DIM;
            xls[cc][r][k] = x[((long)b*SEQLEN + (long)(c0+cc)*CHUNK)*INPUT_DIM + j];
        }
        for (int q = tid; q < 8*64; q += 128) {
            int cc = q >> 6, i = (q >> 3) & 7, n = q & 7;
            Cls[cc][i][n] = Ct[((long)b*SEQLEN + (long)(c0+cc)*CHUNK + i)*8 + n];
        }
        if (tid < 64) {
            int cc = tid >> 3, i = tid & 7;
            els[cc][i] = cAe[((long)b*SEQLEN + (long)(c0+cc)*CHUNK + i)*32 + h];
        }
        // phase A: 8 sequential state steps, recording hprev
        float Svr[8], dcr[8];
        #pragma unroll
        for (int cc = 0; cc < 8; ++cc) {
            Svr[cc] = Sg[sgbase + (size_t)(c0+cc)*4096];
            dcr[cc] = cdec[(b*NC + c0 + cc)*32 + h];
        }
        #pragma unroll
        for (int cc = 0; cc < 8; ++cc) {
            hls[cc][pA][nA] = s;
            s = s*dcr[cc] + Svr[cc];
        }
        __syncthreads();
        // phase B: per chunk, thread (i,p): z-GEMM, silu, dot(hprev, C), pool
        #pragma unroll 2
        for (int cc = 0; cc < 8; ++cc) {
            float z = zb;
            #pragma unroll
            for (int kk = 0; kk < 14; ++kk) {
                float4 xr = *(const float4*)&xls[cc][iB][kk*4];
                z += w[kk*4+0]*xr.x + w[kk*4+1]*xr.y + w[kk*4+2]*xr.z + w[kk*4+3]*xr.w;
            }
            z += w[56]*xls[cc][iB][56];
            float sz = z / (1.f + expf(-z));
            float dot = 0.f;
            #pragma unroll
            for (int n = 0; n < 8; ++n) dot += hls[cc][pB][n]*Cls[cc][iB][n];
            acc += (double)(dot * els[cc][iB] * sz);
        }
    }
    red[tid] = acc;
    __syncthreads();
    if (tid < 16) {
        double t = 0.0;
        for (int i = 0; i < 8; ++i) t += red[i*16 + tid];
        partial_inter[(size_t)b*512 + h*HEADDIM + tid] = t;
    }
}

// ---------------------------------------------------------------------------
// K4: fp64 reduce of partials -> pooled; final = pooled @ W_oc.T + b_cls
// ---------------------------------------------------------------------------
__global__ __launch_bounds__(512) void final_kernel(
    const float* __restrict__ partial_intra,  // [B*NC][512]
    const double* __restrict__ partial_inter, // [B][512]
    const float* __restrict__ W_oc,           // [6][512]
    const float* __restrict__ b_cls,          // [6]
    float* __restrict__ out)                  // [B][6]
{
    __shared__ double pooled[512];
    const int b = blockIdx.x, tid = threadIdx.x;
    double ssum = 0.0;
    for (int c = 0; c < NC; ++c)
        ssum += (double)partial_intra[((size_t)b*NC + c)*512 + tid];
    ssum += partial_inter[(size_t)b*512 + tid];
    pooled[tid] = ssum * (1.0/(double)SEQLEN);
    __syncthreads();
    if (tid < OUT_SIZE*64) {
        const int o = tid >> 6, l = tid & 63;
        double acc = 0.0;
        for (int m = l; m < 512; m += 64)
            acc += pooled[m] * (double)W_oc[o*512 + m];
        #pragma unroll
        for (int off = 32; off > 0; off >>= 1)
            acc += __shfl_down(acc, off);
        if (l == 0) out[b*OUT_SIZE + o] = (float)(acc + (double)b_cls[o]);
    }
}

// ---------------------------------------------------------------------------
extern "C" void kernel_launch(void* const* d_in, const int* in_sizes, int n_in,
                              void* d_out, int out_size, void* d_ws, size_t ws_size,
                              hipStream_t stream)
{
    const float* x        = (const float*)d_in[0];
    const float* W_in     = (const float*)d_in[1];
    const float* b_in     = (const float*)d_in[2];
    const float* W_inproj = (const float*)d_in[3];
    const float* conv_w   = (const float*)d_in[4];
    const float* conv_b   = (const float*)d_in[5];
    const float* dt_bias  = (const float*)d_in[6];
    const float* A_log    = (const float*)d_in[7];
    const float* Dvec     = (const float*)d_in[8];
    const float* W_out    = (const float*)d_in[9];
    const float* W_cls    = (const float*)d_in[10];
    const float* b_cls    = (const float*)d_in[11];
    float* out = (float*)d_out;

    char* ws = (char*)d_ws;
    size_t off = 0;
    auto alloc = [&](size_t bytes) -> void* {
        void* p = ws + off;
        off += (bytes + 255) & ~(size_t)255;
        return p;
    };
    float*  Sg    = (float*) alloc((size_t)BATCH*NC*32*128*4);    // 134.2 MB
    float*  cdecb = (float*) alloc((size_t)BATCH*NC*32*4);        // 1.0 MB
    float*  Ctb   = (float*) alloc((size_t)NTOK*8*4);             // 2.1 MB
    float*  cAeb  = (float*) alloc((size_t)NTOK*32*4);            // 8.4 MB
    float*  pIn   = (float*) alloc((size_t)BATCH*NC*512*4);       // 16.8 MB
    double* pIt   = (double*)alloc((size_t)BATCH*512*8);          // 64 KB
    float*  WcT   = (float*) alloc((size_t)INPUT_DIM*D_INPROJ*4);
    float*  bcomb = (float*) alloc((size_t)D_INPROJ*4);
    float*  Woc   = (float*) alloc((size_t)OUT_SIZE*D_INNER*4);
    if (off > ws_size) return;   // graceful diagnostic: absmax-fail instead of memory fault

    precompute_kernel<<<D_INPROJ + D_INNER, 64, 0, stream>>>(W_in, b_in, W_inproj, W_out, W_cls, WcT, bcomb, Woc);
    chunk_kernel<<<BATCH*NC, 256, 0, stream>>>(x, WcT, bcomb, conv_w, conv_b, dt_bias, A_log, Dvec,
                                               Sg, cdecb, Ctb, cAeb, pIn);
    scanpool_kernel<<<BATCH*32, 128, 0, stream>>>(x, WcT, bcomb, Sg, cdecb, Ctb, cAeb, pIt);
    final_kernel<<<BATCH, 512, 0, stream>>>(pIn, pIt, Woc, b_cls, out);
}

// Round 3
// 773.675 us; speedup vs baseline: 1.3967x; 1.3967x over previous
//
#include <hip/hip_runtime.h>
#include <math.h>

#define BATCH 16
#define SEQLEN 4096
#define INPUT_DIM 57
#define D_MODEL 256
#define D_INNER 512
#define D_STATE 8
#define HEADDIM 16
#define NHEADS 32
#define CHUNK 8
#define NC (SEQLEN/CHUNK)          // 512
#define CONV_DIM 528               // D_INNER + 2*D_STATE
#define D_INPROJ 1072              // 2*D_INNER + 2*D_STATE + NHEADS
#define OUT_SIZE 6
#define NTOK (BATCH*SEQLEN)        // 65536
#define SEG 32                     // chunks per scan segment
#define NSEG (NC/SEG)              // 16

static __device__ const int tri_i_tab[36] = {0,1,1,2,2,2,3,3,3,3,4,4,4,4,4,5,5,5,5,5,5,6,6,6,6,6,6,6,7,7,7,7,7,7,7,7};
static __device__ const int tri_j_tab[36] = {0,0,1,0,1,2,0,1,2,3,0,1,2,3,4,0,1,2,3,4,5,0,1,2,3,4,5,6,0,1,2,3,4,5,6,7};

// ---------------------------------------------------------------------------
// P0: fold W_in into W_inproj (K=57 GEMM), fold W_out into W_cls.
// ---------------------------------------------------------------------------
__global__ void precompute_kernel(const float* __restrict__ W_in,
                                  const float* __restrict__ b_in,
                                  const float* __restrict__ W_inproj,
                                  const float* __restrict__ W_out,
                                  const float* __restrict__ W_cls,
                                  float* __restrict__ WcT,    // [57][1072]
                                  float* __restrict__ b_comb, // [1072]
                                  float* __restrict__ W_oc)   // [6][512]
{
    int blk = blockIdx.x;
    int t = threadIdx.x;
    if (blk < D_INPROJ) {
        int n = blk;
        if (t < INPUT_DIM) {
            double acc = 0.0;
            for (int m = 0; m < D_MODEL; ++m)
                acc += (double)W_inproj[n*D_MODEL+m] * (double)W_in[m*INPUT_DIM+t];
            WcT[t*D_INPROJ + n] = (float)acc;
        } else if (t == INPUT_DIM) {
            double acc = 0.0;
            for (int m = 0; m < D_MODEL; ++m)
                acc += (double)W_inproj[n*D_MODEL+m] * (double)b_in[m];
            b_comb[n] = (float)acc;
        }
    } else {
        int d = blk - D_INPROJ;
        if (t < OUT_SIZE) {
            double acc = 0.0;
            for (int m = 0; m < D_MODEL; ++m)
                acc += (double)W_cls[t*D_MODEL+m] * (double)W_out[m*D_INNER+d];
            W_oc[t*D_INNER + d] = (float)acc;
        }
    }
}

// ---------------------------------------------------------------------------
// A1: per (batch, chunk) block: in-proj micro-GEMM (K=57), conv+silu,
// softplus(dt), cA cumsum, intra attention + D*x, silu(z) gating + pooled
// fp32 partial, state contribution S, chunk_dec, C and exp(cA).
// ---------------------------------------------------------------------------
__global__ __launch_bounds__(256) void chunk_kernel(
    const float* __restrict__ x,       // [NTOK][57]
    const float* __restrict__ WcT,     // [57][1072]
    const float* __restrict__ bcomb,   // [1072]
    const float* __restrict__ conv_w,  // [528][4]
    const float* __restrict__ conv_b,  // [528]
    const float* __restrict__ dt_bias, // [32]
    const float* __restrict__ A_log,   // [32]
    const float* __restrict__ Dvec,    // [32]
    float* __restrict__ Sg,            // [B][NC][32][16][8]
    float* __restrict__ cdec,          // [B][NC][32]
    float* __restrict__ Ct,            // [NTOK][8]
    float* __restrict__ cAe_g,         // [NTOK][32]
    float* __restrict__ partial_intra) // [B*NC][512]
{
    __shared__ __attribute__((aligned(16))) float xsT[57][12];
    __shared__ __attribute__((aligned(16))) float stage[11][560];
    __shared__ __attribute__((aligned(16))) float zsh[8][512];
    __shared__ __attribute__((aligned(16))) float xsilu[8][512];
    __shared__ float Bs[8][8], Cs[8][8];
    __shared__ float dts[8][32], cAl[8][32];
    __shared__ float CBl[8][8];
    __shared__ float scl[8][8][32];
    __shared__ float gco[8][32];

    const int bc  = blockIdx.x;            // b*NC + c
    const int b   = bc >> 9, c = bc & (NC-1);
    const int tid = threadIdx.x;
    const long t0 = (long)b*SEQLEN + (long)c*CHUNK;

    for (int idx = tid; idx < 11*INPUT_DIM; idx += 256) {
        int r = idx / INPUT_DIM, k = idx - r*INPUT_DIM;
        float v = (c == 0 && r < 3) ? 0.f : x[(t0 - 3 + r)*INPUT_DIM + k];
        xsT[k][r + 1] = v;
    }
    __syncthreads();

    {
        const bool has2 = (tid < 48);
        const int  n2   = has2 ? tid + 512 : 512;
        float accz0[8], accz1[8];
        float accx0[11], accx1[11], accx2[11];
        {
            const float bz0 = bcomb[tid], bz1 = bcomb[tid+256];
            const float bx0 = bcomb[512+tid], bx1 = bcomb[768+tid], bx2 = bcomb[512+n2];
            #pragma unroll
            for (int i = 0; i < 8; ++i) { accz0[i] = bz0; accz1[i] = bz1; }
            #pragma unroll
            for (int r = 0; r < 11; ++r) {
                float h0 = (c == 0 && r < 3) ? 0.f : 1.f;
                accx0[r] = bx0*h0; accx1[r] = bx1*h0; accx2[r] = bx2*h0;
            }
        }
        for (int k = 0; k < INPUT_DIM; ++k) {
            const float4 va = *(const float4*)&xsT[k][0];
            const float4 vb = *(const float4*)&xsT[k][4];
            const float4 vc = *(const float4*)&xsT[k][8];
            const float* wrow = &WcT[(size_t)k*D_INPROJ];
            const float wz0 = wrow[tid], wz1 = wrow[tid+256];
            const float wx0 = wrow[512+tid], wx1 = wrow[768+tid], wx2 = wrow[512+n2];
            const float xm0=vb.x, xm1=vb.y, xm2=vb.z, xm3=vb.w, xm4=vc.x, xm5=vc.y, xm6=vc.z, xm7=vc.w;
            accz0[0]+=wz0*xm0; accz0[1]+=wz0*xm1; accz0[2]+=wz0*xm2; accz0[3]+=wz0*xm3;
            accz0[4]+=wz0*xm4; accz0[5]+=wz0*xm5; accz0[6]+=wz0*xm6; accz0[7]+=wz0*xm7;
            accz1[0]+=wz1*xm0; accz1[1]+=wz1*xm1; accz1[2]+=wz1*xm2; accz1[3]+=wz1*xm3;
            accz1[4]+=wz1*xm4; accz1[5]+=wz1*xm5; accz1[6]+=wz1*xm6; accz1[7]+=wz1*xm7;
            accx0[0]+=wx0*va.y; accx0[1]+=wx0*va.z; accx0[2]+=wx0*va.w;
            accx1[0]+=wx1*va.y; accx1[1]+=wx1*va.z; accx1[2]+=wx1*va.w;
            accx2[0]+=wx2*va.y; accx2[1]+=wx2*va.z; accx2[2]+=wx2*va.w;
            accx0[3]+=wx0*xm0; accx0[4]+=wx0*xm1; accx0[5]+=wx0*xm2; accx0[6]+=wx0*xm3;
            accx0[7]+=wx0*xm4; accx0[8]+=wx0*xm5; accx0[9]+=wx0*xm6; accx0[10]+=wx0*xm7;
            accx1[3]+=wx1*xm0; accx1[4]+=wx1*xm1; accx1[5]+=wx1*xm2; accx1[6]+=wx1*xm3;
            accx1[7]+=wx1*xm4; accx1[8]+=wx1*xm5; accx1[9]+=wx1*xm6; accx1[10]+=wx1*xm7;
            accx2[3]+=wx2*xm0; accx2[4]+=wx2*xm1; accx2[5]+=wx2*xm2; accx2[6]+=wx2*xm3;
            accx2[7]+=wx2*xm4; accx2[8]+=wx2*xm5; accx2[9]+=wx2*xm6; accx2[10]+=wx2*xm7;
        }
        #pragma unroll
        for (int i = 0; i < 8; ++i) { zsh[i][tid] = accz0[i]; zsh[i][tid+256] = accz1[i]; }
        #pragma unroll
        for (int r = 0; r < 11; ++r) { stage[r][tid] = accx0[r]; stage[r][tid+256] = accx1[r]; }
        if (has2) {
            #pragma unroll
            for (int r = 0; r < 11; ++r) stage[r][tid+512] = accx2[r];
        }
    }
    __syncthreads();

    for (int ch = tid; ch < CONV_DIM; ch += 256) {
        const float w0 = conv_w[ch*4+0], w1 = conv_w[ch*4+1];
        const float w2 = conv_w[ch*4+2], w3 = conv_w[ch*4+3];
        const float cb = conv_b[ch];
        float s0 = stage[0][ch], s1 = stage[1][ch], s2 = stage[2][ch];
        #pragma unroll
        for (int i = 0; i < CHUNK; ++i) {
            float s3 = stage[3+i][ch];
            float v = cb + s0*w0 + s1*w1 + s2*w2 + s3*w3;
            v = v / (1.f + __expf(-v));               // silu
            if (ch < D_INNER)       xsilu[i][ch] = v;
            else if (ch < 520)      Bs[i][ch-512] = v;
            else { Cs[i][ch-520] = v; Ct[(t0+i)*8 + (ch-520)] = v; }
            s0 = s1; s1 = s2; s2 = s3;
        }
    }
    {
        int i = tid >> 5, h = tid & 31;
        float raw = stage[3+i][528+h] + dt_bias[h];
        dts[i][h] = (raw > 20.f) ? raw : log1pf(__expf(raw));
    }
    __syncthreads();

    if (tid < 32) {
        const int h = tid;
        const float Ah = -__expf(A_log[h]);
        float ca = 0.f, e = 1.f;
        #pragma unroll
        for (int i = 0; i < CHUNK; ++i) {
            ca += dts[i][h] * Ah;
            cAl[i][h] = ca;
            e = __expf(ca);
            cAe_g[(t0+i)*32 + h] = e;
        }
        cdec[bc*32 + h] = e;
    } else if (tid < 96) {
        int ij = tid - 32, i = ij >> 3, j = ij & 7;
        float s = 0.f;
        #pragma unroll
        for (int n = 0; n < D_STATE; ++n) s += Cs[i][n]*Bs[j][n];
        CBl[i][j] = s;
    }
    __syncthreads();

    for (int idx = tid; idx < 36*32; idx += 256) {
        int pr = idx >> 5, h = idx & 31;
        int i = tri_i_tab[pr], j = tri_j_tab[pr];
        scl[i][j][h] = CBl[i][j] * __expf(cAl[i][h] - cAl[j][h]) * dts[j][h];
    }
    {
        int j = tid >> 5, h = tid & 31;
        gco[j][h] = __expf(cAl[7][h] - cAl[j][h]) * dts[j][h];
    }
    __syncthreads();

    const int h  = tid >> 3;
    const int p0 = (tid & 7) * 2;
    const int d0 = tid * 2;
    float2 xv[8];
    #pragma unroll
    for (int j = 0; j < CHUNK; ++j) xv[j] = *(const float2*)&xsilu[j][d0];
    const float Dv = Dvec[h];

    float pa0 = 0.f, pa1 = 0.f;
    #pragma unroll
    for (int i = 0; i < CHUNK; ++i) {
        float a0 = Dv*xv[i].x, a1 = Dv*xv[i].y;
        #pragma unroll
        for (int j = 0; j < CHUNK; ++j) {
            if (j > i) break;
            float s = scl[i][j][h];
            a0 += s*xv[j].x; a1 += s*xv[j].y;
        }
        float2 zz = *(const float2*)&zsh[i][d0];
        float sz0 = zz.x / (1.f + __expf(-zz.x));
        float sz1 = zz.y / (1.f + __expf(-zz.y));
        pa0 += a0*sz0; pa1 += a1*sz1;
    }
    partial_intra[(size_t)bc*512 + d0]     = pa0;
    partial_intra[(size_t)bc*512 + d0 + 1] = pa1;

    float tj0[8], tj1[8];
    #pragma unroll
    for (int j = 0; j < CHUNK; ++j) {
        float g = gco[j][h];
        tj0[j] = g*xv[j].x; tj1[j] = g*xv[j].y;
    }
    float sn0[8], sn1[8];
    #pragma unroll
    for (int n = 0; n < D_STATE; ++n) {
        float s = 0.f, t = 0.f;
        #pragma unroll
        for (int j = 0; j < CHUNK; ++j) { float bv = Bs[j][n]; s += tj0[j]*bv; t += tj1[j]*bv; }
        sn0[n] = s; sn1[n] = t;
    }
    size_t sb = ((size_t)bc*32 + h)*128 + (size_t)p0*8;
    *(float4*)&Sg[sb+0]  = make_float4(sn0[0],sn0[1],sn0[2],sn0[3]);
    *(float4*)&Sg[sb+4]  = make_float4(sn0[4],sn0[5],sn0[6],sn0[7]);
    *(float4*)&Sg[sb+8]  = make_float4(sn1[0],sn1[1],sn1[2],sn1[3]);
    *(float4*)&Sg[sb+12] = make_float4(sn1[4],sn1[5],sn1[6],sn1[7]);
}

// ---------------------------------------------------------------------------
// A2 pass 1: segmented scan + pooling. One block per (b,h,seg); 32 chunks
// sequential inside, 8192 blocks parallel. Produces per-segment summaries:
// A (decay product), Sloc (local end state), G (linear response of pooled
// output to incoming state), ploc (locally pooled part).
// Thread roles: gamma (p,n) = (tid>>3, tid&7); beta (i,p) = (tid>>4, tid&15).
// ---------------------------------------------------------------------------
__global__ __launch_bounds__(128) void scanseg_kernel(
    const float* __restrict__ x,       // [NTOK][57]
    const float* __restrict__ WcT,     // [57][1072]
    const float* __restrict__ bcomb,   // [1072]
    const float* __restrict__ Sg,      // [B][NC][32][128]
    const float* __restrict__ cdec,    // [B][NC][32]
    const float* __restrict__ Ct,      // [NTOK][8]
    const float* __restrict__ cAe,     // [NTOK][32]
    float* __restrict__ Sloc,          // [8192][128]
    float* __restrict__ Gseg,          // [8192][128]
    float* __restrict__ Aseg,          // [8192]
    float* __restrict__ ploc)          // [8192][16]
{
    const int blk = blockIdx.x;             // (b*32+h)*NSEG + seg
    const int seg = blk & (NSEG-1);
    const int bh  = blk >> 4;
    const int b = bh >> 5, h = bh & 31;
    const int tid = threadIdx.x;
    const int pA = tid >> 3, nA = tid & 7;   // gamma role
    const int iB = tid >> 4, pB = tid & 15;  // beta role

    __shared__ __attribute__((aligned(16))) float xls[4][8][60];
    __shared__ __attribute__((aligned(16))) float Cls[4][8][8];
    __shared__ float els[4][8];
    __shared__ float sls[2][16][9];
    __shared__ float wls[8][16];
    __shared__ float red[128];

    float w[INPUT_DIM];
    #pragma unroll
    for (int k = 0; k < INPUT_DIM; ++k) w[k] = WcT[(size_t)k*D_INPROJ + h*HEADDIM + pB];
    const float zb = bcomb[h*HEADDIM + pB];

    float s = 0.f, P = 1.f, G = 0.f, pooled = 0.f;
    const int c0 = seg*SEG;

    for (int cg = 0; cg < SEG/4; ++cg) {
        const int cbase = c0 + cg*4;
        const long tg = (long)b*SEQLEN + (long)cbase*CHUNK;   // first token of group
        __syncthreads();                       // protect LDS reuse across groups
        for (int q = tid; q < 4*8*INPUT_DIM; q += 128) {
            int cc = q / (8*INPUT_DIM);
            int r  = q - cc*(8*INPUT_DIM);
            int i  = r / INPUT_DIM, k = r - i*INPUT_DIM;
            xls[cc][i][k] = x[tg*INPUT_DIM + q];
        }
        if (tid < 64)
            ((float4*)Cls)[tid] = ((const float4*)&Ct[tg*8])[tid];
        if (tid < 32) {
            int cc = tid >> 3, i = tid & 7;
            els[cc][i] = cAe[(tg + cc*8 + i)*32 + h];
        }
        #pragma unroll
        for (int cc = 0; cc < 4; ++cc) {
            const int c = cbase + cc;
            const float Sval = Sg[((size_t)(b*NC + c)*32 + h)*128 + tid];
            const float d    = cdec[(b*NC + c)*32 + h];
            const int pbuf = cc & 1;
            sls[pbuf][pA][nA] = s;             // alpha: expose pre-chunk state
            __syncthreads();                   // B2: sls + group loads visible
            // beta: z-GEMM, silu, dot(hprev,C), pooled, weight for g
            float z = zb;
            #pragma unroll
            for (int kk = 0; kk < 14; ++kk) {
                float4 xr = *(const float4*)&xls[cc][iB][kk*4];
                z += w[kk*4+0]*xr.x + w[kk*4+1]*xr.y + w[kk*4+2]*xr.z + w[kk*4+3]*xr.w;
            }
            z += w[56]*xls[cc][iB][56];
            float sz = z / (1.f + __expf(-z));
            float dot = 0.f;
            #pragma unroll
            for (int n = 0; n < 8; ++n) dot += sls[pbuf][pB][n]*Cls[cc][iB][n];
            float we = els[cc][iB] * sz;
            pooled += dot * we;
            wls[iB][pB] = we;
            __syncthreads();                   // B3: wls visible
            // gamma: g = sum_i wls[i][p]*C[i][n]; G += P*g; advance state
            float g = 0.f;
            #pragma unroll
            for (int i = 0; i < 8; ++i) g += wls[i][pA]*Cls[cc][i][nA];
            G += P * g;
            P *= d;
            s = s*d + Sval;
        }
    }
    Sloc[(size_t)blk*128 + tid] = s;
    Gseg[(size_t)blk*128 + tid] = G;
    if (tid == 0) Aseg[blk] = P;
    red[tid] = pooled;
    __syncthreads();
    if (tid < 16) {
        float t = 0.f;
        #pragma unroll
        for (int i = 0; i < 8; ++i) t += red[i*16 + tid];
        ploc[(size_t)blk*16 + tid] = t;
    }
}

// ---------------------------------------------------------------------------
// A2 pass 2: combine 16 segments per (b,h). Tiny.
// ---------------------------------------------------------------------------
__global__ __launch_bounds__(128) void scancomb_kernel(
    const float* __restrict__ Sloc,    // [8192][128]
    const float* __restrict__ Gseg,    // [8192][128]
    const float* __restrict__ Aseg,    // [8192]
    const float* __restrict__ ploc,    // [8192][16]
    double* __restrict__ partial_inter)// [B][512] = [8192]
{
    __shared__ double red[128];
    const int bh = blockIdx.x;
    const int tid = threadIdx.x;
    float s = 0.f;
    double acc = 0.0;
    for (int seg = 0; seg < NSEG; ++seg) {
        size_t base = (size_t)(bh*NSEG + seg);
        float Gv = Gseg[base*128 + tid];
        float Av = Aseg[base];
        float Sv = Sloc[base*128 + tid];
        acc += (double)(s * Gv);
        s = s*Av + Sv;
    }
    red[tid] = acc;
    __syncthreads();
    if (tid < 16) {
        double t = 0.0;
        #pragma unroll
        for (int n = 0; n < 8; ++n) t += red[tid*8 + n];
        for (int seg = 0; seg < NSEG; ++seg)
            t += (double)ploc[(size_t)(bh*NSEG + seg)*16 + tid];
        partial_inter[(size_t)bh*16 + tid] = t;
    }
}

// ---------------------------------------------------------------------------
// Parallel reduction of intra partials: [B*NC][512] -> [B][32][512]
// ---------------------------------------------------------------------------
__global__ __launch_bounds__(256) void reduce_intra_kernel(
    const float* __restrict__ pIn,     // [B*NC][512]
    float* __restrict__ pred)          // [B][32][512]
{
    const int g = blockIdx.x & 31;
    const int b = blockIdx.x >> 5;
    const int tid = threadIdx.x;
    for (int col = tid; col < 512; col += 256) {
        float s = 0.f;
        #pragma unroll 4
        for (int c = 0; c < 16; ++c)
            s += pIn[((size_t)b*NC + g*16 + c)*512 + col];
        pred[((size_t)(b*32) + g)*512 + col] = s;
    }
}

// ---------------------------------------------------------------------------
// K4: fp64 combine -> pooled; final = pooled @ W_oc.T + b_cls
// ---------------------------------------------------------------------------
__global__ __launch_bounds__(512) void final_kernel(
    const float* __restrict__ pred,           // [B][32][512]
    const double* __restrict__ partial_inter, // [B][512]
    const float* __restrict__ W_oc,           // [6][512]
    const float* __restrict__ b_cls,          // [6]
    float* __restrict__ out)                  // [B][6]
{
    __shared__ double pooled[512];
    const int b = blockIdx.x, tid = threadIdx.x;
    double ssum = 0.0;
    for (int g = 0; g < 32; ++g)
        ssum += (double)pred[((size_t)(b*32) + g)*512 + tid];
    ssum += partial_inter[(size_t)b*512 + tid];
    pooled[tid] = ssum * (1.0/(double)SEQLEN);
    __syncthreads();
    if (tid < OUT_SIZE*64) {
        const int o = tid >> 6, l = tid & 63;
        double acc = 0.0;
        for (int m = l; m < 512; m += 64)
            acc += pooled[m] * (double)W_oc[o*512 + m];
        #pragma unroll
        for (int off = 32; off > 0; off >>= 1)
            acc += __shfl_down(acc, off);
        if (l == 0) out[b*OUT_SIZE + o] = (float)(acc + (double)b_cls[o]);
    }
}

// ---------------------------------------------------------------------------
extern "C" void kernel_launch(void* const* d_in, const int* in_sizes, int n_in,
                              void* d_out, int out_size, void* d_ws, size_t ws_size,
                              hipStream_t stream)
{
    const float* x        = (const float*)d_in[0];
    const float* W_in     = (const float*)d_in[1];
    const float* b_in     = (const float*)d_in[2];
    const float* W_inproj = (const float*)d_in[3];
    const float* conv_w   = (const float*)d_in[4];
    const float* conv_b   = (const float*)d_in[5];
    const float* dt_bias  = (const float*)d_in[6];
    const float* A_log    = (const float*)d_in[7];
    const float* Dvec     = (const float*)d_in[8];
    const float* W_out    = (const float*)d_in[9];
    const float* W_cls    = (const float*)d_in[10];
    const float* b_cls    = (const float*)d_in[11];
    float* out = (float*)d_out;

    char* ws = (char*)d_ws;
    size_t off = 0;
    auto alloc = [&](size_t bytes) -> void* {
        void* p = ws + off;
        off += (bytes + 255) & ~(size_t)255;
        return p;
    };
    float*  Sg    = (float*) alloc((size_t)BATCH*NC*32*128*4);        // 134.2 MB
    float*  cdecb = (float*) alloc((size_t)BATCH*NC*32*4);            // 1.0 MB
    float*  Ctb   = (float*) alloc((size_t)NTOK*8*4);                 // 2.1 MB
    float*  cAeb  = (float*) alloc((size_t)NTOK*32*4);                // 8.4 MB
    float*  pIn   = (float*) alloc((size_t)BATCH*NC*512*4);           // 16.8 MB
    float*  pred  = (float*) alloc((size_t)BATCH*32*512*4);           // 1.0 MB
    double* pIt   = (double*)alloc((size_t)BATCH*512*8);              // 64 KB
    float*  SlocB = (float*) alloc((size_t)BATCH*NHEADS*NSEG*128*4);  // 4.2 MB
    float*  GsegB = (float*) alloc((size_t)BATCH*NHEADS*NSEG*128*4);  // 4.2 MB
    float*  AsegB = (float*) alloc((size_t)BATCH*NHEADS*NSEG*4);      // 32 KB
    float*  plocB = (float*) alloc((size_t)BATCH*NHEADS*NSEG*16*4);   // 0.5 MB
    float*  WcT   = (float*) alloc((size_t)INPUT_DIM*D_INPROJ*4);
    float*  bcomb = (float*) alloc((size_t)D_INPROJ*4);
    float*  Woc   = (float*) alloc((size_t)OUT_SIZE*D_INNER*4);
    if (off > ws_size) return;   // diagnostic: absmax-fail instead of fault

    precompute_kernel<<<D_INPROJ + D_INNER, 64, 0, stream>>>(W_in, b_in, W_inproj, W_out, W_cls, WcT, bcomb, Woc);
    chunk_kernel<<<BATCH*NC, 256, 0, stream>>>(x, WcT, bcomb, conv_w, conv_b, dt_bias, A_log, Dvec,
                                               Sg, cdecb, Ctb, cAeb, pIn);
    scanseg_kernel<<<BATCH*NHEADS*NSEG, 128, 0, stream>>>(x, WcT, bcomb, Sg, cdecb, Ctb, cAeb,
                                                          SlocB, GsegB, AsegB, plocB);
    scancomb_kernel<<<BATCH*NHEADS, 128, 0, stream>>>(SlocB, GsegB, AsegB, plocB, pIt);
    reduce_intra_kernel<<<BATCH*32, 256, 0, stream>>>(pIn, pred);
    final_kernel<<<BATCH, 512, 0, stream>>>(pred, pIt, Woc, b_cls, out);
}

// Round 4
// 545.327 us; speedup vs baseline: 1.9816x; 1.4187x over previous
//
#include <hip/hip_runtime.h>
#include <math.h>

#define BATCH 16
#define SEQLEN 4096
#define INPUT_DIM 57
#define D_MODEL 256
#define D_INNER 512
#define D_STATE 8
#define HEADDIM 16
#define NHEADS 32
#define CHUNK 8
#define NC (SEQLEN/CHUNK)          // 512
#define CONV_DIM 528
#define D_INPROJ 1072
#define OUT_SIZE 6
#define NTOK (BATCH*SEQLEN)        // 65536
#define SEG 32                     // chunks per scan segment
#define NSEG (NC/SEG)              // 16

static __device__ const int tri_i_tab[36] = {0,1,1,2,2,2,3,3,3,3,4,4,4,4,4,5,5,5,5,5,5,6,6,6,6,6,6,6,7,7,7,7,7,7,7,7};
static __device__ const int tri_j_tab[36] = {0,0,1,0,1,2,0,1,2,3,0,1,2,3,4,0,1,2,3,4,5,0,1,2,3,4,5,6,0,1,2,3,4,5,6,7};

__device__ __forceinline__ unsigned f2bf(float f) {   // RNE bf16, finite inputs
    unsigned v = __float_as_uint(f);
    return (v + 0x7fffu + ((v >> 16) & 1u)) >> 16;
}

// ---------------------------------------------------------------------------
// P0: fold W_in into W_inproj (K=57 GEMM), fold W_out into W_cls.
// ---------------------------------------------------------------------------
__global__ void precompute_kernel(const float* __restrict__ W_in,
                                  const float* __restrict__ b_in,
                                  const float* __restrict__ W_inproj,
                                  const float* __restrict__ W_out,
                                  const float* __restrict__ W_cls,
                                  float* __restrict__ WcT,    // [57][1072]
                                  float* __restrict__ b_comb, // [1072]
                                  float* __restrict__ W_oc)   // [6][512]
{
    int blk = blockIdx.x;
    int t = threadIdx.x;
    if (blk < D_INPROJ) {
        int n = blk;
        if (t < INPUT_DIM) {
            double acc = 0.0;
            for (int m = 0; m < D_MODEL; ++m)
                acc += (double)W_inproj[n*D_MODEL+m] * (double)W_in[m*INPUT_DIM+t];
            WcT[t*D_INPROJ + n] = (float)acc;
        } else if (t == INPUT_DIM) {
            double acc = 0.0;
            for (int m = 0; m < D_MODEL; ++m)
                acc += (double)W_inproj[n*D_MODEL+m] * (double)b_in[m];
            b_comb[n] = (float)acc;
        }
    } else {
        int d = blk - D_INPROJ;
        if (t < OUT_SIZE) {
            double acc = 0.0;
            for (int m = 0; m < D_MODEL; ++m)
                acc += (double)W_cls[t*D_MODEL+m] * (double)W_out[m*D_INNER+d];
            W_oc[t*D_INNER + d] = (float)acc;
        }
    }
}

// ---------------------------------------------------------------------------
// A1: per (batch, chunk). Register-resident pipeline: thread owns cols
// {2tid, 2tid+1} of both z and x through GEMM -> conv -> silu -> intra ->
// gating -> pooling. Produces packed bf16 (S,g) pairs for the scan.
// LDS ~16 KB, 4 barriers.
// ---------------------------------------------------------------------------
__global__ __launch_bounds__(256) void chunk_kernel(
    const float* __restrict__ x,       // [NTOK][57]
    const float* __restrict__ WcT,     // [57][1072]
    const float* __restrict__ bcomb,   // [1072]
    const float* __restrict__ conv_w,  // [528][4]
    const float* __restrict__ conv_b,  // [528]
    const float* __restrict__ dt_bias, // [32]
    const float* __restrict__ A_log,   // [32]
    const float* __restrict__ Dvec,    // [32]
    unsigned* __restrict__ SGg,        // [B*NC][32][128] packed: lo=S, hi=g
    float* __restrict__ cdec,          // [B*NC][32]
    float* __restrict__ partial_intra) // [B*NC][512]
{
    __shared__ __attribute__((aligned(16))) float xsT[INPUT_DIM][12]; // [k][slot]; slot r+1 = row r
    __shared__ float Bs[8][8], Cs[8][8];
    __shared__ float dts[8][32], cAl[8][32], els[8][32];
    __shared__ float CBl[8][8];
    __shared__ float scl[8][8][32];
    __shared__ float gco[8][32];

    const int bc  = blockIdx.x;            // b*NC + c
    const int b   = bc >> 9, c = bc & (NC-1);
    const int tid = threadIdx.x;
    const long t0 = (long)b*SEQLEN + (long)c*CHUNK;

    // ---- stage x rows (t0-3 .. t0+7) transposed ----
    for (int idx = tid; idx < 11*INPUT_DIM; idx += 256) {
        int r = idx / INPUT_DIM, k = idx - r*INPUT_DIM;
        float v = (c == 0 && r < 3) ? 0.f : x[(t0 - 3 + r)*INPUT_DIM + k];
        xsT[k][r + 1] = v;
    }
    __syncthreads();

    // ---- GEMM: z cols 2tid,2tid+1 (8 main rows); x cols 512+2tid,+1 (11 rows);
    //      extra col 1024+tid (B/C/dt) for wave 0 only ----
    float2 accz[8];
    float2 accx[11];
    float  acce[11];
    const int ecol = 1024 + ((tid < 48) ? tid : 0);
    {
        float2 bz = *(const float2*)&bcomb[2*tid];
        float2 bx = *(const float2*)&bcomb[512 + 2*tid];
        float  be = bcomb[ecol];
        #pragma unroll
        for (int i = 0; i < 8; ++i) accz[i] = bz;
        #pragma unroll
        for (int r = 0; r < 11; ++r) {
            float h0 = (c == 0 && r < 3) ? 0.f : 1.f;
            accx[r].x = bx.x*h0; accx[r].y = bx.y*h0;
            acce[r] = be*h0;
        }
    }
    for (int k = 0; k < INPUT_DIM; ++k) {
        const float4 va = *(const float4*)&xsT[k][0];
        const float4 vb = *(const float4*)&xsT[k][4];
        const float4 vc = *(const float4*)&xsT[k][8];
        const float* wrow = &WcT[(size_t)k*D_INPROJ];
        const float2 wz = *(const float2*)&wrow[2*tid];
        const float2 wx = *(const float2*)&wrow[512 + 2*tid];
        const float xm[11] = {va.y,va.z,va.w, vb.x,vb.y,vb.z,vb.w, vc.x,vc.y,vc.z,vc.w};
        #pragma unroll
        for (int r = 0; r < 11; ++r) { accx[r].x += wx.x*xm[r]; accx[r].y += wx.y*xm[r]; }
        #pragma unroll
        for (int i = 0; i < 8; ++i)  { accz[i].x += wz.x*xm[3+i]; accz[i].y += wz.y*xm[3+i]; }
        if (tid < 64) {                       // wave-0-contained extra col
            const float we = wrow[ecol];
            #pragma unroll
            for (int r = 0; r < 11; ++r) acce[r] += we*xm[r];
        }
    }

    // ---- B/C conv+silu (tid<16); dt softplus+cumsum chain (tid 16..47) ----
    if (tid < 16) {
        const int ch = 512 + tid;
        const float4 cw = *(const float4*)&conv_w[ch*4];
        const float cb = conv_b[ch];
        float s0 = acce[0], s1 = acce[1], s2 = acce[2];
        #pragma unroll
        for (int i = 0; i < 8; ++i) {
            float s3 = acce[3+i];
            float v = cb + s0*cw.x + s1*cw.y + s2*cw.z + s3*cw.w;
            v = v / (1.f + __expf(-v));
            if (tid < 8) Bs[i][tid] = v; else Cs[i][tid-8] = v;
            s0 = s1; s1 = s2; s2 = s3;
        }
    } else if (tid < 48) {
        const int h = tid - 16;
        const float Ah = -__expf(A_log[h]);
        float ca = 0.f, e = 1.f;
        #pragma unroll
        for (int i = 0; i < 8; ++i) {
            float raw = acce[3+i] + dt_bias[h];
            float dt = (raw > 20.f) ? raw : log1pf(__expf(raw));
            dts[i][h] = dt;
            ca += dt * Ah;
            cAl[i][h] = ca;
            e = __expf(ca);
            els[i][h] = e;
        }
        cdec[bc*32 + h] = e;
    }

    // ---- x conv + silu, all in registers ----
    float2 xv[8];
    {
        const float4 cwa = *(const float4*)&conv_w[8*tid];
        const float4 cwb = *(const float4*)&conv_w[8*tid + 4];
        const float2 cb2 = *(const float2*)&conv_b[2*tid];
        float2 s0 = accx[0], s1 = accx[1], s2 = accx[2];
        #pragma unroll
        for (int i = 0; i < 8; ++i) {
            float2 s3 = accx[3+i];
            float vx = cb2.x + s0.x*cwa.x + s1.x*cwa.y + s2.x*cwa.z + s3.x*cwa.w;
            float vy = cb2.y + s0.y*cwb.x + s1.y*cwb.y + s2.y*cwb.z + s3.y*cwb.w;
            xv[i].x = vx / (1.f + __expf(-vx));
            xv[i].y = vy / (1.f + __expf(-vy));
            s0 = s1; s1 = s2; s2 = s3;
        }
    }
    __syncthreads();

    // ---- CB = C B^T ----
    if (tid < 64) {
        int i = tid >> 3, j = tid & 7;
        float s = 0.f;
        #pragma unroll
        for (int n = 0; n < 8; ++n) s += Cs[i][n]*Bs[j][n];
        CBl[i][j] = s;
    }
    __syncthreads();

    // ---- score coefficients (lower tri) + state-gather coefficients ----
    for (int idx = tid; idx < 36*32; idx += 256) {
        int pr = idx >> 5, h = idx & 31;
        int i = tri_i_tab[pr], j = tri_j_tab[pr];
        scl[i][j][h] = CBl[i][j] * __expf(cAl[i][h] - cAl[j][h]) * dts[j][h];
    }
    {
        int j = tid >> 5, h = tid & 31;
        gco[j][h] = __expf(cAl[7][h] - cAl[j][h]) * dts[j][h];
    }
    __syncthreads();

    // ---- per-thread tail: head h = tid>>3, p slots p0,p0+1 ----
    const int h  = tid >> 3;
    const int p0 = (tid & 7) * 2;
    const float Dv = Dvec[h];

    float sz0[8], sz1[8];
    #pragma unroll
    for (int i = 0; i < 8; ++i) {
        sz0[i] = accz[i].x / (1.f + __expf(-accz[i].x));
        sz1[i] = accz[i].y / (1.f + __expf(-accz[i].y));
    }

    // intra attention + D*x, gated + pooled
    float pa0 = 0.f, pa1 = 0.f;
    #pragma unroll
    for (int i = 0; i < 8; ++i) {
        float a0 = Dv*xv[i].x, a1 = Dv*xv[i].y;
        #pragma unroll
        for (int j = 0; j < 8; ++j) {
            if (j > i) break;
            float s = scl[i][j][h];
            a0 += s*xv[j].x; a1 += s*xv[j].y;
        }
        pa0 += a0*sz0[i]; pa1 += a1*sz1[i];
    }
    *(float2*)&partial_intra[(size_t)bc*512 + 2*tid] = make_float2(pa0, pa1);

    // g[p][n] = sum_i silu(z)_i[p] * e_i[h] * C_i[n]
    float g0[8], g1[8];
    #pragma unroll
    for (int n = 0; n < 8; ++n) { g0[n] = 0.f; g1[n] = 0.f; }
    #pragma unroll
    for (int i = 0; i < 8; ++i) {
        float e = els[i][h];
        float w0 = sz0[i]*e, w1 = sz1[i]*e;
        #pragma unroll
        for (int n = 0; n < 8; ++n) { g0[n] += w0*Cs[i][n]; g1[n] += w1*Cs[i][n]; }
    }

    // S[p][n] = sum_j gco_j * x_j[p] * B_j[n]
    float sn0[8], sn1[8];
    #pragma unroll
    for (int n = 0; n < 8; ++n) { sn0[n] = 0.f; sn1[n] = 0.f; }
    #pragma unroll
    for (int j = 0; j < 8; ++j) {
        float g = gco[j][h];
        float tj0 = g*xv[j].x, tj1 = g*xv[j].y;
        #pragma unroll
        for (int n = 0; n < 8; ++n) { float bv = Bs[j][n]; sn0[n] += tj0*bv; sn1[n] += tj1*bv; }
    }

    // pack bf16 pairs (lo = S, hi = g) and store 64 B contiguous
    unsigned u[16];
    #pragma unroll
    for (int n = 0; n < 8; ++n) {
        u[n]   = (f2bf(g0[n]) << 16) | f2bf(sn0[n]);
        u[8+n] = (f2bf(g1[n]) << 16) | f2bf(sn1[n]);
    }
    unsigned* dst = &SGg[((size_t)bc*32 + h)*128 + p0*8];
    #pragma unroll
    for (int q = 0; q < 4; ++q)
        *(uint4*)&dst[q*4] = *(uint4*)&u[q*4];
}

// ---------------------------------------------------------------------------
// A2 pass 1: element-parallel segmented scan. Zero barriers, zero LDS in the
// main loop; the only serial chain is 2 FMAs/step. 8192 blocks x 128 thr.
// ---------------------------------------------------------------------------
__global__ __launch_bounds__(128) void scanseg_kernel(
    const unsigned* __restrict__ SGg,  // [B*NC][32][128] packed
    const float* __restrict__ cdec,    // [B*NC][32]
    float* __restrict__ Sloc,          // [8192][128]
    float* __restrict__ Gseg,          // [8192][128]
    float* __restrict__ Aseg,          // [8192]
    float* __restrict__ ploc)          // [8192][16]
{
    const int blk = blockIdx.x;             // (b*32+h)*NSEG + seg
    const int seg = blk & (NSEG-1);
    const int bh  = blk >> 4;
    const int b = bh >> 5, h = bh & 31;
    const int tid = threadIdx.x;            // element e = p*8+n
    const int c0 = seg*SEG;

    float s = 0.f, P = 1.f, G = 0.f, pooled = 0.f;
    const unsigned* src = &SGg[((size_t)(b*NC + c0)*32 + h)*128 + tid];
    const float* dsrc = &cdec[(b*NC + c0)*32 + h];

    #pragma unroll 4
    for (int cc = 0; cc < SEG; ++cc) {
        unsigned u = src[(size_t)cc*4096];
        float d = dsrc[cc*32];
        float Sv = __uint_as_float(u << 16);
        float gv = __uint_as_float(u & 0xffff0000u);
        pooled += s * gv;          // hprev (state BEFORE this chunk) . g
        G += P * gv;               // linear response to incoming state
        P *= d;
        s = s*d + Sv;
    }
    Sloc[(size_t)blk*128 + tid] = s;
    Gseg[(size_t)blk*128 + tid] = G;
    if (tid == 0) Aseg[blk] = P;

    float t = pooled;              // reduce over n (groups of 8 lanes)
    t += __shfl_down(t, 4, 8);
    t += __shfl_down(t, 2, 8);
    t += __shfl_down(t, 1, 8);
    if ((tid & 7) == 0) ploc[(size_t)blk*16 + (tid >> 3)] = t;
}

// ---------------------------------------------------------------------------
// A2 pass 2: combine 16 segments per (b,h). Tiny.
// ---------------------------------------------------------------------------
__global__ __launch_bounds__(128) void scancomb_kernel(
    const float* __restrict__ Sloc,    // [8192][128]
    const float* __restrict__ Gseg,    // [8192][128]
    const float* __restrict__ Aseg,    // [8192]
    const float* __restrict__ ploc,    // [8192][16]
    double* __restrict__ partial_inter)// [B][512]
{
    __shared__ double red[128];
    const int bh = blockIdx.x;
    const int tid = threadIdx.x;
    float s = 0.f;
    double acc = 0.0;
    for (int seg = 0; seg < NSEG; ++seg) {
        size_t base = (size_t)(bh*NSEG + seg);
        float Gv = Gseg[base*128 + tid];
        float Av = Aseg[base];
        float Sv = Sloc[base*128 + tid];
        acc += (double)(s * Gv);
        s = s*Av + Sv;
    }
    red[tid] = acc;
    __syncthreads();
    if (tid < 16) {
        double t = 0.0;
        #pragma unroll
        for (int n = 0; n < 8; ++n) t += red[tid*8 + n];
        for (int seg = 0; seg < NSEG; ++seg)
            t += (double)ploc[(size_t)(bh*NSEG + seg)*16 + tid];
        partial_inter[(size_t)bh*16 + tid] = t;
    }
}

// ---------------------------------------------------------------------------
// Parallel reduction of intra partials: [B*NC][512] -> [B][32][512]
// ---------------------------------------------------------------------------
__global__ __launch_bounds__(256) void reduce_intra_kernel(
    const float* __restrict__ pIn,     // [B*NC][512]
    float* __restrict__ pred)          // [B][32][512]
{
    const int g = blockIdx.x & 31;
    const int b = blockIdx.x >> 5;
    const int tid = threadIdx.x;
    for (int col = tid; col < 512; col += 256) {
        float s = 0.f;
        #pragma unroll 4
        for (int c = 0; c < 16; ++c)
            s += pIn[((size_t)b*NC + g*16 + c)*512 + col];
        pred[((size_t)(b*32) + g)*512 + col] = s;
    }
}

// ---------------------------------------------------------------------------
// K4: fp64 combine -> pooled; final = pooled @ W_oc.T + b_cls
// ---------------------------------------------------------------------------
__global__ __launch_bounds__(512) void final_kernel(
    const float* __restrict__ pred,           // [B][32][512]
    const double* __restrict__ partial_inter, // [B][512]
    const float* __restrict__ W_oc,           // [6][512]
    const float* __restrict__ b_cls,          // [6]
    float* __restrict__ out)                  // [B][6]
{
    __shared__ double pooled[512];
    const int b = blockIdx.x, tid = threadIdx.x;
    double ssum = 0.0;
    for (int g = 0; g < 32; ++g)
        ssum += (double)pred[((size_t)(b*32) + g)*512 + tid];
    ssum += partial_inter[(size_t)b*512 + tid];
    pooled[tid] = ssum * (1.0/(double)SEQLEN);
    __syncthreads();
    if (tid < OUT_SIZE*64) {
        const int o = tid >> 6, l = tid & 63;
        double acc = 0.0;
        for (int m = l; m < 512; m += 64)
            acc += pooled[m] * (double)W_oc[o*512 + m];
        #pragma unroll
        for (int off = 32; off > 0; off >>= 1)
            acc += __shfl_down(acc, off);
        if (l == 0) out[b*OUT_SIZE + o] = (float)(acc + (double)b_cls[o]);
    }
}

// ---------------------------------------------------------------------------
extern "C" void kernel_launch(void* const* d_in, const int* in_sizes, int n_in,
                              void* d_out, int out_size, void* d_ws, size_t ws_size,
                              hipStream_t stream)
{
    const float* x        = (const float*)d_in[0];
    const float* W_in     = (const float*)d_in[1];
    const float* b_in     = (const float*)d_in[2];
    const float* W_inproj = (const float*)d_in[3];
    const float* conv_w   = (const float*)d_in[4];
    const float* conv_b   = (const float*)d_in[5];
    const float* dt_bias  = (const float*)d_in[6];
    const float* A_log    = (const float*)d_in[7];
    const float* Dvec     = (const float*)d_in[8];
    const float* W_out    = (const float*)d_in[9];
    const float* W_cls    = (const float*)d_in[10];
    const float* b_cls    = (const float*)d_in[11];
    float* out = (float*)d_out;

    char* ws = (char*)d_ws;
    size_t off = 0;
    auto alloc = [&](size_t bytes) -> void* {
        void* p = ws + off;
        off += (bytes + 255) & ~(size_t)255;
        return p;
    };
    unsigned* SGg   = (unsigned*)alloc((size_t)BATCH*NC*32*128*4);      // 134.2 MB
    float*  cdecb = (float*) alloc((size_t)BATCH*NC*32*4);              // 1.0 MB
    float*  pIn   = (float*) alloc((size_t)BATCH*NC*512*4);             // 16.8 MB
    float*  pred  = (float*) alloc((size_t)BATCH*32*512*4);             // 1.0 MB
    double* pIt   = (double*)alloc((size_t)BATCH*512*8);                // 64 KB
    float*  SlocB = (float*) alloc((size_t)BATCH*NHEADS*NSEG*128*4);    // 4.2 MB
    float*  GsegB = (float*) alloc((size_t)BATCH*NHEADS*NSEG*128*4);    // 4.2 MB
    float*  AsegB = (float*) alloc((size_t)BATCH*NHEADS*NSEG*4);        // 32 KB
    float*  plocB = (float*) alloc((size_t)BATCH*NHEADS*NSEG*16*4);     // 0.5 MB
    float*  WcT   = (float*) alloc((size_t)INPUT_DIM*D_INPROJ*4);
    float*  bcomb = (float*) alloc((size_t)D_INPROJ*4);
    float*  Woc   = (float*) alloc((size_t)OUT_SIZE*D_INNER*4);
    if (off > ws_size) return;   // diagnostic: absmax-fail instead of fault

    precompute_kernel<<<D_INPROJ + D_INNER, 64, 0, stream>>>(W_in, b_in, W_inproj, W_out, W_cls, WcT, bcomb, Woc);
    chunk_kernel<<<BATCH*NC, 256, 0, stream>>>(x, WcT, bcomb, conv_w, conv_b, dt_bias, A_log, Dvec,
                                               SGg, cdecb, pIn);
    scanseg_kernel<<<BATCH*NHEADS*NSEG, 128, 0, stream>>>(SGg, cdecb, SlocB, GsegB, AsegB, plocB);
    scancomb_kernel<<<BATCH*NHEADS, 128, 0, stream>>>(SlocB, GsegB, AsegB, plocB, pIt);
    reduce_intra_kernel<<<BATCH*32, 256, 0, stream>>>(pIn, pred);
    final_kernel<<<BATCH, 512, 0, stream>>>(pred, pIt, Woc, b_cls, out);
}